// Round 3
// baseline (182.176 us; speedup 1.0000x reference)
//
#include <hip/hip_runtime.h>
#include <hip/hip_bf16.h>
#include <math.h>

#define Bt 8
#define Ct 64
#define Ht 128
#define Wt 128
#define Ot 64
#define HWt (Ht*Wt)

typedef __bf16 bf16x8 __attribute__((ext_vector_type(8)));
typedef float  f32x4  __attribute__((ext_vector_type(4)));

// fp32 -> bf16 bits, round-to-nearest-even, integer ops only
__device__ __forceinline__ uint f2bf_bits(float v) {
    uint u = __float_as_uint(v);
    uint lsb = (u >> 16) & 1u;
    return (u + 0x7fffu + lsb) >> 16;
}
__device__ __forceinline__ ushort f2bf(float v) {
    return (ushort)f2bf_bits(v);
}

// ---------------- prep ----------------
// blocks 0..1023: transpose x NCHW fp32 -> xTb NHWC bf16  [b][y][x][c]
//   mapping b = blk&7 so XCD that writes batch b is the XCD that reads it (L2 affinity)
// blocks 1024.. : weight reshapes
__global__ __launch_bounds__(256) void prep_kernel(
    const float* __restrict__ x, const float* __restrict__ w_off,
    const float* __restrict__ w_mask, const float* __restrict__ w_dcn,
    ushort* __restrict__ xTb, ushort* __restrict__ wOffB, ushort* __restrict__ wMainB)
{
    int blk = blockIdx.x;
    int t = threadIdx.x;
    if (blk < 1024) {
        __shared__ float L[64][128];
        int b = blk & 7, y = blk >> 3;
        const float* xb = x + (size_t)b * 1048576 + y * 128;
#pragma unroll
        for (int it = 0; it < 8; ++it) {
            int i = it * 256 + t;
            int c = i >> 5, x4 = i & 31;
            *(float4*)&L[c][x4 * 4] = *(const float4*)&xb[(size_t)c * HWt + x4 * 4];
        }
        __syncthreads();
        int px = t >> 1, half = (t & 1) * 32;
        union { ushort u[32]; uint4 q[4]; } pk;
#pragma unroll
        for (int i = 0; i < 32; ++i) pk.u[i] = f2bf(L[half + i][px]);
        uint4* dst = (uint4*)(xTb + ((size_t)(b * 128 + y) * 128 + px) * 64 + half);
        dst[0] = pk.q[0]; dst[1] = pk.q[1]; dst[2] = pk.q[2]; dst[3] = pk.q[3];
    } else {
        int i = (blk - 1024) * 256 + t;
        if (i < 9 * 32 * 64) {
            int c = i & 63, ch = (i >> 6) & 31, k = i >> 11;
            float v = 0.f;
            if (ch < 18)      v = w_off[(ch * 64 + c) * 9 + k];
            else if (ch < 27) v = w_mask[((ch - 18) * 64 + c) * 9 + k];
            wOffB[i] = f2bf(v);
        } else {
            int j = i - 18432;
            if (j < 9 * 64 * 64) {
                int c = j & 63, o = (j >> 6) & 63, k = j >> 12;
                wMainB[j] = f2bf(w_dcn[(o * 64 + c) * 9 + k]);
            }
        }
    }
}

// ---------------- phase-2 tap helpers ----------------
struct Tap { uint o[4]; float w[4]; };

__device__ __forceinline__ void tap_ctx(int k, int y, float fx, int cq8,
                                        const float* __restrict__ odmRow, Tap& tp) {
    int ky = k / 3, kx = k - ky * 3;
    float dyv = odmRow[k];
    float dxv = odmRow[9 + k];
    float mkv = odmRow[18 + k];
    float py  = (float)(y + ky - 1) + dyv;
    float pxf = fx + (float)(kx - 1) + dxv;
    float y0f = floorf(py), x0f = floorf(pxf);
    float wy1 = py - y0f, wy0 = 1.f - wy1;
    float wx1 = pxf - x0f, wx0 = 1.f - wx1;
    bool vy0 = (y0f >= 0.f) && (y0f <= 127.f);
    bool vy1 = (y0f >= -1.f) && (y0f <= 126.f);
    bool vx0 = (x0f >= 0.f) && (x0f <= 127.f);
    bool vx1 = (x0f >= -1.f) && (x0f <= 126.f);
    tp.w[0] = (vy0 && vx0) ? wy0 * wx0 * mkv : 0.f;
    tp.w[1] = (vy0 && vx1) ? wy0 * wx1 * mkv : 0.f;
    tp.w[2] = (vy1 && vx0) ? wy1 * wx0 * mkv : 0.f;
    tp.w[3] = (vy1 && vx1) ? wy1 * wx1 * mkv : 0.f;
    int yi0 = (int)y0f, xi0 = (int)x0f;
    int y0c = min(max(yi0, 0), 127), y1c = min(max(yi0 + 1, 0), 127);
    int x0c = min(max(xi0, 0), 127), x1c = min(max(xi0 + 1, 0), 127);
    tp.o[0] = (uint)(((y0c << 7) + x0c) * 64 + cq8);
    tp.o[1] = (uint)(((y0c << 7) + x1c) * 64 + cq8);
    tp.o[2] = (uint)(((y1c << 7) + x0c) * 64 + cq8);
    tp.o[3] = (uint)(((y1c << 7) + x1c) * 64 + cq8);
}

__device__ __forceinline__ void tap_issue(const ushort* __restrict__ xbb, const Tap& tp, uint4* D) {
#pragma unroll
    for (int c = 0; c < 4; ++c)
#pragma unroll
        for (int ks = 0; ks < 2; ++ks)
            D[c * 2 + ks] = *(const uint4*)(xbb + tp.o[c] + ks * 32);
}

// exact round-1 fmaf chain (bit-identical numerics)
__device__ __forceinline__ void tap_blend(const Tap& tp, const uint4* D, bf16x8* afr) {
    float w00 = tp.w[0], w01 = tp.w[1], w10 = tp.w[2], w11 = tp.w[3];
#pragma unroll
    for (int ks = 0; ks < 2; ++ks) {
        union { uint4 q; uint u[4]; } v00, v01, v10, v11, wr;
        v00.q = D[0 * 2 + ks];
        v01.q = D[1 * 2 + ks];
        v10.q = D[2 * 2 + ks];
        v11.q = D[3 * 2 + ks];
#pragma unroll
        for (int j = 0; j < 4; ++j) {
            float f00l = __uint_as_float(v00.u[j] << 16);
            float f00h = __uint_as_float(v00.u[j] & 0xffff0000u);
            float f01l = __uint_as_float(v01.u[j] << 16);
            float f01h = __uint_as_float(v01.u[j] & 0xffff0000u);
            float f10l = __uint_as_float(v10.u[j] << 16);
            float f10h = __uint_as_float(v10.u[j] & 0xffff0000u);
            float f11l = __uint_as_float(v11.u[j] << 16);
            float f11h = __uint_as_float(v11.u[j] & 0xffff0000u);
            float vl = w00 * f00l;
            vl = fmaf(w01, f01l, vl); vl = fmaf(w10, f10l, vl); vl = fmaf(w11, f11l, vl);
            float vh = w00 * f00h;
            vh = fmaf(w01, f01h, vh); vh = fmaf(w10, f10h, vh); vh = fmaf(w11, f11h, vh);
            wr.u[j] = (f2bf_bits(vh) << 16) | f2bf_bits(vl);
        }
        afr[ks] = __builtin_bit_cast(bf16x8, wr.q);
    }
}

// ---------------- fused: offset/mask conv -> LDS -> bilinear sample + MFMA ----------------
// block: 512 thr, one (b,y) row of 128 px, 8 waves x M=16.
// phase 1: 27-channel offset conv (N=32, K=576), results -> odm LDS [128][28] f32.
// phase 2: main conv N=64 (4 tiles), K=576, odm read from LDS; 1-tap-deep software
//          pipeline (tap k+1 gathers issued before tap k blend; no sched intrinsics).
// __launch_bounds__(512,4): allow 128 VGPR so the prefetch regs stay live (2 blk/CU).
// LDS overlay (38,912 B total):
//   phase1: smem[0..18431]  = wOff 288x64 swizzled (36,864 B)
//   phase2: smem[0..12287]  = wS group 192x64 swizzled (24,576 B)
//           smem[12288..]   = odm floats [128][28]      (14,336 B)
__global__ __launch_bounds__(512, 4) void dcn_fused_kernel(
    const ushort* __restrict__ xTb, const ushort* __restrict__ wOffB,
    const ushort* __restrict__ wMainB, const float* __restrict__ b_off,
    const float* __restrict__ b_mask, const float* __restrict__ b_dcn,
    float* __restrict__ out)
{
    __shared__ ushort smem[19456];          // 38,912 B
    float* odmF = (float*)&smem[12288];     // 3584 floats, bytes [24576, 38912)

    int t = threadIdx.x;
    int blk = blockIdx.x;
    int b = blk & 7, y = blk >> 3;          // XCD batch affinity
    int wv = t >> 6, ln = t & 63;
    int m = ln & 15, cq = ln >> 4;
    int px = wv * 16 + m;
    int cq8 = cq * 8;

    const ushort* xbb = xTb + (size_t)b * 1048576;

    // ---------- phase 1: offset/mask conv (round-1 verified code, unchanged) ----------
    {
        // stage all 9 taps of wOff: 2304 16B-chunks, swizzled
#pragma unroll
        for (int it = 0; it < 5; ++it) {
            int j = it * 512 + t;
            if (j < 2304) {
                int row = j >> 3, gch = j & 7;
                int col = ((gch + row) & 7) * 8;
                *(uint4*)&smem[row * 64 + col] = *(const uint4*)&wOffB[(size_t)row * 64 + gch * 8];
            }
        }
        __syncthreads();

        f32x4 acc0 = {0.f, 0.f, 0.f, 0.f};
        f32x4 acc1 = {0.f, 0.f, 0.f, 0.f};
#pragma unroll
        for (int k = 0; k < 9; ++k) {
            int ky = k / 3, kx = k - ky * 3;
            int yy = y + ky - 1;
            int xx = px + kx - 1;
            bool ok = ((unsigned)yy < 128u) && ((unsigned)xx < 128u);
            const ushort* arow = xbb + ((size_t)((yy << 7) + xx)) * 64;
            bf16x8 afr[2];
#pragma unroll
            for (int ks = 0; ks < 2; ++ks) {
                int c0 = ks * 32 + cq * 8;
                uint4 v = {0u, 0u, 0u, 0u};
                if (ok) v = *(const uint4*)&arow[c0];
                afr[ks] = __builtin_bit_cast(bf16x8, v);
            }
            int br0 = k * 32 + m;
            int br1 = br0 + 16;
#pragma unroll
            for (int ks = 0; ks < 2; ++ks) {
                int gs = ks * 4 + cq;
                bf16x8 b0 = __builtin_bit_cast(bf16x8,
                    *(const uint4*)&smem[br0 * 64 + ((gs + br0) & 7) * 8]);
                bf16x8 b1 = __builtin_bit_cast(bf16x8,
                    *(const uint4*)&smem[br1 * 64 + ((gs + br1) & 7) * 8]);
                acc0 = __builtin_amdgcn_mfma_f32_16x16x32_bf16(afr[ks], b0, acc0, 0, 0, 0);
                acc1 = __builtin_amdgcn_mfma_f32_16x16x32_bf16(afr[ks], b1, acc1, 0, 0, 0);
            }
        }
        __syncthreads();   // all wL reads complete: odm region + wS region may now be written

        // epilogue -> odm LDS.  slots: 0..8 = dy[k], 9..17 = dx[k], 18..26 = mask[k]
        int n = m;
        int pxl = wv * 16 + (cq << 2);
#pragma unroll
        for (int r = 0; r < 4; ++r) {
            int pp = pxl + r;
            odmF[pp * 28 + (n & 1) * 9 + (n >> 1)] = acc0[r] + b_off[n];
            int ch = 16 + n;
            float v1 = acc1[r];
            if (ch < 18) {
                odmF[pp * 28 + (ch & 1) * 9 + (ch >> 1)] = v1 + b_off[ch];
            } else if (ch < 27) {
                float val = v1 + b_mask[ch - 18];
                odmF[pp * 28 + 18 + (ch - 18)] = 1.f / (1.f + __expf(-val));
            }
        }

        // stage main-weight group 0 (disjoint from odm region) while epilogue drains
#pragma unroll
        for (int it = 0; it < 3; ++it) {
            int j = it * 512 + t;
            int row = j >> 3, gch = j & 7;
            *(uint4*)&smem[row * 64 + ((gch + row) & 7) * 8] =
                *(const uint4*)&wMainB[(size_t)row * 64 + gch * 8];
        }
        __syncthreads();   // odm + group-0 weights visible
    }

    // ---------- phase 2: bilinear sample + main MFMA (1-tap pipelined) ----------
    f32x4 acc[4];
#pragma unroll
    for (int i = 0; i < 4; ++i) acc[i] = f32x4{0.f, 0.f, 0.f, 0.f};

    float fx = (float)px;
    const float* odmRow = odmF + px * 28;

    Tap  T[2];
    uint4 D[2][8];

    tap_ctx(0, y, fx, cq8, odmRow, T[0]);
    tap_issue(xbb, T[0], D[0]);

#pragma unroll
    for (int k = 0; k < 9; ++k) {
        const int par = k & 1;

        // prefetch next tap's gathers before this tap's blend/MFMA
        if (k < 8) {
            tap_ctx(k + 1, y, fx, cq8, odmRow, T[par ^ 1]);
            tap_issue(xbb, T[par ^ 1], D[par ^ 1]);
        }

        // group boundary: restage wS (prefetched gathers complete during the drain)
        if (k == 3 || k == 6) {
            __syncthreads();
            const int gg = k / 3;
#pragma unroll
            for (int it = 0; it < 3; ++it) {
                int j = it * 512 + t;
                int row = j >> 3, gch = j & 7;
                *(uint4*)&smem[row * 64 + ((gch + row) & 7) * 8] =
                    *(const uint4*)&wMainB[(size_t)(gg * 192 + row) * 64 + gch * 8];
            }
            __syncthreads();
        }

        bf16x8 afr[2];
        tap_blend(T[par], D[par], afr);

        const int tl = k - (k / 3) * 3;
#pragma unroll
        for (int ks = 0; ks < 2; ++ks) {
            int chk = ks * 4 + cq;           // 16B channel-chunk index
#pragma unroll
            for (int nt = 0; nt < 4; ++nt) {
                int brow = tl * 64 + nt * 16 + m;
                bf16x8 bb = __builtin_bit_cast(bf16x8,
                    *(const uint4*)&smem[brow * 64 + ((chk + brow) & 7) * 8]);
                acc[nt] = __builtin_amdgcn_mfma_f32_16x16x32_bf16(afr[ks], bb, acc[nt], 0, 0, 0);
            }
        }
    }

    // epilogue: direct coalesced float4 stores from C layout
#pragma unroll
    for (int nt = 0; nt < 4; ++nt) {
        int o = nt * 16 + m;
        float bias = b_dcn[o];
        float4 v;
        v.x = acc[nt][0] + bias;
        v.y = acc[nt][1] + bias;
        v.z = acc[nt][2] + bias;
        v.w = acc[nt][3] + bias;
        float* orow = out + ((size_t)(b * 64 + o) << 14) + (y << 7) + wv * 16 + cq * 4;
        *(float4*)orow = v;
    }
}

extern "C" void kernel_launch(void* const* d_in, const int* in_sizes, int n_in,
                              void* d_out, int out_size, void* d_ws, size_t ws_size,
                              hipStream_t stream) {
    const float* x      = (const float*)d_in[0];
    const float* w_off  = (const float*)d_in[1];
    const float* b_off  = (const float*)d_in[2];
    const float* w_mask = (const float*)d_in[3];
    const float* b_mask = (const float*)d_in[4];
    const float* w_dcn  = (const float*)d_in[5];
    const float* b_dcn  = (const float*)d_in[6];
    float* out = (float*)d_out;

    ushort* xTb    = (ushort*)d_ws;                  // 8.4M bf16
    ushort* wOffB  = xTb + (size_t)Bt * HWt * 64;    // 18432
    ushort* wMainB = wOffB + 18432;                  // 36864

    hipLaunchKernelGGL(prep_kernel, dim3(1024 + 216), dim3(256), 0, stream,
                       x, w_off, w_mask, w_dcn, xTb, wOffB, wMainB);
    hipLaunchKernelGGL(dcn_fused_kernel, dim3(1024), dim3(512), 0, stream,
                       xTb, wOffB, wMainB, b_off, b_mask, b_dcn, out);
}

// Round 6
// 181.950 us; speedup vs baseline: 1.0012x; 1.0012x over previous
//
#include <hip/hip_runtime.h>
#include <hip/hip_bf16.h>
#include <math.h>

#define Bt 8
#define Ct 64
#define Ht 128
#define Wt 128
#define Ot 64
#define HWt (Ht*Wt)

typedef __bf16 bf16x8 __attribute__((ext_vector_type(8)));
typedef float  f32x4  __attribute__((ext_vector_type(4)));

// fp32 -> bf16 bits, round-to-nearest-even, integer ops only
__device__ __forceinline__ uint f2bf_bits(float v) {
    uint u = __float_as_uint(v);
    uint lsb = (u >> 16) & 1u;
    return (u + 0x7fffu + lsb) >> 16;
}
__device__ __forceinline__ ushort f2bf(float v) {
    return (ushort)f2bf_bits(v);
}

// ---------------- prep ----------------
// blocks 0..1023: transpose x NCHW fp32 -> xTb NHWC bf16  [b][y][x][c]
//   mapping b = blk&7 so XCD that writes batch b is the XCD that reads it (L2 affinity)
// blocks 1024.. : weight reshapes
__global__ __launch_bounds__(256) void prep_kernel(
    const float* __restrict__ x, const float* __restrict__ w_off,
    const float* __restrict__ w_mask, const float* __restrict__ w_dcn,
    ushort* __restrict__ xTb, ushort* __restrict__ wOffB, ushort* __restrict__ wMainB)
{
    int blk = blockIdx.x;
    int t = threadIdx.x;
    if (blk < 1024) {
        __shared__ float L[64][128];
        int b = blk & 7, y = blk >> 3;
        const float* xb = x + (size_t)b * 1048576 + y * 128;
#pragma unroll
        for (int it = 0; it < 8; ++it) {
            int i = it * 256 + t;
            int c = i >> 5, x4 = i & 31;
            *(float4*)&L[c][x4 * 4] = *(const float4*)&xb[(size_t)c * HWt + x4 * 4];
        }
        __syncthreads();
        int px = t >> 1, half = (t & 1) * 32;
        union { ushort u[32]; uint4 q[4]; } pk;
#pragma unroll
        for (int i = 0; i < 32; ++i) pk.u[i] = f2bf(L[half + i][px]);
        uint4* dst = (uint4*)(xTb + ((size_t)(b * 128 + y) * 128 + px) * 64 + half);
        dst[0] = pk.q[0]; dst[1] = pk.q[1]; dst[2] = pk.q[2]; dst[3] = pk.q[3];
    } else {
        int i = (blk - 1024) * 256 + t;
        if (i < 9 * 32 * 64) {
            int c = i & 63, ch = (i >> 6) & 31, k = i >> 11;
            float v = 0.f;
            if (ch < 18)      v = w_off[(ch * 64 + c) * 9 + k];
            else if (ch < 27) v = w_mask[((ch - 18) * 64 + c) * 9 + k];
            wOffB[i] = f2bf(v);
        } else {
            int j = i - 18432;
            if (j < 9 * 64 * 64) {
                int c = j & 63, o = (j >> 6) & 63, k = j >> 12;
                wMainB[j] = f2bf(w_dcn[(o * 64 + c) * 9 + k]);
            }
        }
    }
}

// ---------------- phase-2 tap helpers ----------------
struct Tap { uint o[4]; float w[4]; };

__device__ __forceinline__ void tap_ctx(int k, int y, float fx, int cq8,
                                        const float* __restrict__ odmRow, Tap& tp) {
    int ky = k / 3, kx = k - ky * 3;
    float dyv = odmRow[k];
    float dxv = odmRow[9 + k];
    float mkv = odmRow[18 + k];
    float py  = (float)(y + ky - 1) + dyv;
    float pxf = fx + (float)(kx - 1) + dxv;
    float y0f = floorf(py), x0f = floorf(pxf);
    float wy1 = py - y0f, wy0 = 1.f - wy1;
    float wx1 = pxf - x0f, wx0 = 1.f - wx1;
    bool vy0 = (y0f >= 0.f) && (y0f <= 127.f);
    bool vy1 = (y0f >= -1.f) && (y0f <= 126.f);
    bool vx0 = (x0f >= 0.f) && (x0f <= 127.f);
    bool vx1 = (x0f >= -1.f) && (x0f <= 126.f);
    tp.w[0] = (vy0 && vx0) ? wy0 * wx0 * mkv : 0.f;
    tp.w[1] = (vy0 && vx1) ? wy0 * wx1 * mkv : 0.f;
    tp.w[2] = (vy1 && vx0) ? wy1 * wx0 * mkv : 0.f;
    tp.w[3] = (vy1 && vx1) ? wy1 * wx1 * mkv : 0.f;
    int yi0 = (int)y0f, xi0 = (int)x0f;
    int y0c = min(max(yi0, 0), 127), y1c = min(max(yi0 + 1, 0), 127);
    int x0c = min(max(xi0, 0), 127), x1c = min(max(xi0 + 1, 0), 127);
    tp.o[0] = (uint)(((y0c << 7) + x0c) * 64 + cq8);
    tp.o[1] = (uint)(((y0c << 7) + x1c) * 64 + cq8);
    tp.o[2] = (uint)(((y1c << 7) + x0c) * 64 + cq8);
    tp.o[3] = (uint)(((y1c << 7) + x1c) * 64 + cq8);
}

// plain loads: compiler tracks them and inserts exact waitcnt (correct under
// any RA copies/spills). Pipelining comes from issue placement + sched_barrier.
__device__ __forceinline__ void tap_issue(const ushort* __restrict__ xbb, const Tap& tp, uint4* D) {
#pragma unroll
    for (int c = 0; c < 4; ++c)
#pragma unroll
        for (int ks = 0; ks < 2; ++ks)
            D[c * 2 + ks] = *(const uint4*)(xbb + tp.o[c] + ks * 32);
}

// exact round-1 fmaf chain (bit-identical numerics)
__device__ __forceinline__ void tap_blend(const Tap& tp, const uint4* D, bf16x8* afr) {
    float w00 = tp.w[0], w01 = tp.w[1], w10 = tp.w[2], w11 = tp.w[3];
#pragma unroll
    for (int ks = 0; ks < 2; ++ks) {
        union { uint4 q; uint u[4]; } v00, v01, v10, v11, wr;
        v00.q = D[0 * 2 + ks];
        v01.q = D[1 * 2 + ks];
        v10.q = D[2 * 2 + ks];
        v11.q = D[3 * 2 + ks];
#pragma unroll
        for (int j = 0; j < 4; ++j) {
            float f00l = __uint_as_float(v00.u[j] << 16);
            float f00h = __uint_as_float(v00.u[j] & 0xffff0000u);
            float f01l = __uint_as_float(v01.u[j] << 16);
            float f01h = __uint_as_float(v01.u[j] & 0xffff0000u);
            float f10l = __uint_as_float(v10.u[j] << 16);
            float f10h = __uint_as_float(v10.u[j] & 0xffff0000u);
            float f11l = __uint_as_float(v11.u[j] << 16);
            float f11h = __uint_as_float(v11.u[j] & 0xffff0000u);
            float vl = w00 * f00l;
            vl = fmaf(w01, f01l, vl); vl = fmaf(w10, f10l, vl); vl = fmaf(w11, f11l, vl);
            float vh = w00 * f00h;
            vh = fmaf(w01, f01h, vh); vh = fmaf(w10, f10h, vh); vh = fmaf(w11, f11h, vh);
            wr.u[j] = (f2bf_bits(vh) << 16) | f2bf_bits(vl);
        }
        afr[ks] = __builtin_bit_cast(bf16x8, wr.q);
    }
}

// ---------------- fused: offset/mask conv -> LDS -> bilinear sample + MFMA ----------------
// block: 512 thr, one (b,y) row of 128 px, 8 waves x M=16.
// phase 1: 27-channel offset conv (N=32, K=576), results -> odm LDS [128][28] f32.
// phase 2: main conv N=64 (4 tiles), K=576, odm read from LDS; 1-tap-deep pipeline:
//          plain loads (compiler-correct waits) + sched_barrier(0) between the
//          prefetch issue and this tap's blend so the scheduler cannot sink the
//          prefetch to its use (round-3 failure mode, VGPR=52).
// __launch_bounds__(512,3): VGPR cap ~170 so the live double-buffer (~64 VGPR)
// fits without spills.
// LDS overlay (38,912 B total):
//   phase1: smem[0..18431]  = wOff 288x64 swizzled (36,864 B)
//   phase2: smem[0..12287]  = wS group 192x64 swizzled (24,576 B)
//           smem[12288..]   = odm floats [128][28]      (14,336 B)
__global__ __launch_bounds__(512, 3) void dcn_fused_kernel(
    const ushort* __restrict__ xTb, const ushort* __restrict__ wOffB,
    const ushort* __restrict__ wMainB, const float* __restrict__ b_off,
    const float* __restrict__ b_mask, const float* __restrict__ b_dcn,
    float* __restrict__ out)
{
    __shared__ ushort smem[19456];          // 38,912 B
    float* odmF = (float*)&smem[12288];     // 3584 floats, bytes [24576, 38912)

    int t = threadIdx.x;
    int blk = blockIdx.x;
    int b = blk & 7, y = blk >> 3;          // XCD batch affinity
    int wv = t >> 6, ln = t & 63;
    int m = ln & 15, cq = ln >> 4;
    int px = wv * 16 + m;
    int cq8 = cq * 8;

    const ushort* xbb = xTb + (size_t)b * 1048576;

    // ---------- phase 1: offset/mask conv (round-3 verified code, unchanged) ----------
    {
#pragma unroll
        for (int it = 0; it < 5; ++it) {
            int j = it * 512 + t;
            if (j < 2304) {
                int row = j >> 3, gch = j & 7;
                int col = ((gch + row) & 7) * 8;
                *(uint4*)&smem[row * 64 + col] = *(const uint4*)&wOffB[(size_t)row * 64 + gch * 8];
            }
        }
        __syncthreads();

        f32x4 acc0 = {0.f, 0.f, 0.f, 0.f};
        f32x4 acc1 = {0.f, 0.f, 0.f, 0.f};
#pragma unroll
        for (int k = 0; k < 9; ++k) {
            int ky = k / 3, kx = k - ky * 3;
            int yy = y + ky - 1;
            int xx = px + kx - 1;
            bool ok = ((unsigned)yy < 128u) && ((unsigned)xx < 128u);
            const ushort* arow = xbb + ((size_t)((yy << 7) + xx)) * 64;
            bf16x8 afr[2];
#pragma unroll
            for (int ks = 0; ks < 2; ++ks) {
                int c0 = ks * 32 + cq * 8;
                uint4 v = {0u, 0u, 0u, 0u};
                if (ok) v = *(const uint4*)&arow[c0];
                afr[ks] = __builtin_bit_cast(bf16x8, v);
            }
            int br0 = k * 32 + m;
            int br1 = br0 + 16;
#pragma unroll
            for (int ks = 0; ks < 2; ++ks) {
                int gs = ks * 4 + cq;
                bf16x8 b0 = __builtin_bit_cast(bf16x8,
                    *(const uint4*)&smem[br0 * 64 + ((gs + br0) & 7) * 8]);
                bf16x8 b1 = __builtin_bit_cast(bf16x8,
                    *(const uint4*)&smem[br1 * 64 + ((gs + br1) & 7) * 8]);
                acc0 = __builtin_amdgcn_mfma_f32_16x16x32_bf16(afr[ks], b0, acc0, 0, 0, 0);
                acc1 = __builtin_amdgcn_mfma_f32_16x16x32_bf16(afr[ks], b1, acc1, 0, 0, 0);
            }
        }
        __syncthreads();   // all wL reads complete: odm region + wS region may now be written

        // epilogue -> odm LDS.  slots: 0..8 = dy[k], 9..17 = dx[k], 18..26 = mask[k]
        int n = m;
        int pxl = wv * 16 + (cq << 2);
#pragma unroll
        for (int r = 0; r < 4; ++r) {
            int pp = pxl + r;
            odmF[pp * 28 + (n & 1) * 9 + (n >> 1)] = acc0[r] + b_off[n];
            int ch = 16 + n;
            float v1 = acc1[r];
            if (ch < 18) {
                odmF[pp * 28 + (ch & 1) * 9 + (ch >> 1)] = v1 + b_off[ch];
            } else if (ch < 27) {
                float val = v1 + b_mask[ch - 18];
                odmF[pp * 28 + 18 + (ch - 18)] = 1.f / (1.f + __expf(-val));
            }
        }

        // stage main-weight group 0 (disjoint from odm region) while epilogue drains
#pragma unroll
        for (int it = 0; it < 3; ++it) {
            int j = it * 512 + t;
            int row = j >> 3, gch = j & 7;
            *(uint4*)&smem[row * 64 + ((gch + row) & 7) * 8] =
                *(const uint4*)&wMainB[(size_t)row * 64 + gch * 8];
        }
        __syncthreads();   // odm + group-0 weights visible
    }

    // ---------- phase 2: bilinear sample + main MFMA (1-tap pipelined, pinned) ----------
    f32x4 acc[4];
#pragma unroll
    for (int i = 0; i < 4; ++i) acc[i] = f32x4{0.f, 0.f, 0.f, 0.f};

    float fx = (float)px;
    const float* odmRow = odmF + px * 28;

    Tap  T[2];
    uint4 D[2][8];

    tap_ctx(0, y, fx, cq8, odmRow, T[0]);
    tap_issue(xbb, T[0], D[0]);

#pragma unroll
    for (int k = 0; k < 9; ++k) {
        const int par = k & 1;

        // prefetch next tap's gathers; fence stops the scheduler sinking them
        // below this tap's blend (semantics-neutral: loads are plain, waits
        // are compiler-inserted).
        if (k < 8) {
            tap_ctx(k + 1, y, fx, cq8, odmRow, T[par ^ 1]);
            tap_issue(xbb, T[par ^ 1], D[par ^ 1]);
            __builtin_amdgcn_sched_barrier(0);
        }

        // group boundary: restage wS (prefetched gathers complete during the
        // __syncthreads vmcnt drain — verified win in round 3)
        if (k == 3 || k == 6) {
            __syncthreads();
            const int gg = k / 3;
#pragma unroll
            for (int it = 0; it < 3; ++it) {
                int j = it * 512 + t;
                int row = j >> 3, gch = j & 7;
                *(uint4*)&smem[row * 64 + ((gch + row) & 7) * 8] =
                    *(const uint4*)&wMainB[(size_t)(gg * 192 + row) * 64 + gch * 8];
            }
            __syncthreads();
        }

        bf16x8 afr[2];
        tap_blend(T[par], D[par], afr);

        const int tl = k - (k / 3) * 3;
#pragma unroll
        for (int ks = 0; ks < 2; ++ks) {
            int chk = ks * 4 + cq;           // 16B channel-chunk index
#pragma unroll
            for (int nt = 0; nt < 4; ++nt) {
                int brow = tl * 64 + nt * 16 + m;
                bf16x8 bb = __builtin_bit_cast(bf16x8,
                    *(const uint4*)&smem[brow * 64 + ((chk + brow) & 7) * 8]);
                acc[nt] = __builtin_amdgcn_mfma_f32_16x16x32_bf16(afr[ks], bb, acc[nt], 0, 0, 0);
            }
        }
    }

    // epilogue: direct coalesced float4 stores from C layout
#pragma unroll
    for (int nt = 0; nt < 4; ++nt) {
        int o = nt * 16 + m;
        float bias = b_dcn[o];
        float4 v;
        v.x = acc[nt][0] + bias;
        v.y = acc[nt][1] + bias;
        v.z = acc[nt][2] + bias;
        v.w = acc[nt][3] + bias;
        float* orow = out + ((size_t)(b * 64 + o) << 14) + (y << 7) + wv * 16 + cq * 4;
        *(float4*)orow = v;
    }
}

extern "C" void kernel_launch(void* const* d_in, const int* in_sizes, int n_in,
                              void* d_out, int out_size, void* d_ws, size_t ws_size,
                              hipStream_t stream) {
    const float* x      = (const float*)d_in[0];
    const float* w_off  = (const float*)d_in[1];
    const float* b_off  = (const float*)d_in[2];
    const float* w_mask = (const float*)d_in[3];
    const float* b_mask = (const float*)d_in[4];
    const float* w_dcn  = (const float*)d_in[5];
    const float* b_dcn  = (const float*)d_in[6];
    float* out = (float*)d_out;

    ushort* xTb    = (ushort*)d_ws;                  // 8.4M bf16
    ushort* wOffB  = xTb + (size_t)Bt * HWt * 64;    // 18432
    ushort* wMainB = wOffB + 18432;                  // 36864

    hipLaunchKernelGGL(prep_kernel, dim3(1024 + 216), dim3(256), 0, stream,
                       x, w_off, w_mask, w_dcn, xTb, wOffB, wMainB);
    hipLaunchKernelGGL(dcn_fused_kernel, dim3(1024), dim3(512), 0, stream,
                       xTb, wOffB, wMainB, b_off, b_mask, b_dcn, out);
}

// Round 7
// 144.370 us; speedup vs baseline: 1.2619x; 1.2603x over previous
//
#include <hip/hip_runtime.h>
#include <hip/hip_bf16.h>
#include <math.h>

#define Bt 8
#define Ct 64
#define Ht 128
#define Wt 128
#define Ot 64
#define HWt (Ht*Wt)

// tile decomposition: 16 rows x 8 cols per block; band = tile + 2px margin
#define BROWS 20
#define BCOLS 12
#define BPX   240            // BROWS*BCOLS
// LDS map (bytes):  band [0,30720) | wOff/wS [30720, ...) | odm [55296,69632)
#define WBASE_U 15360        // ushort index of weight region (byte 30720)
#define ODM_B   55296

typedef __bf16 bf16x8 __attribute__((ext_vector_type(8)));
typedef float  f32x4  __attribute__((ext_vector_type(4)));

// fp32 -> bf16 bits, round-to-nearest-even, integer ops only
__device__ __forceinline__ uint f2bf_bits(float v) {
    uint u = __float_as_uint(v);
    uint lsb = (u >> 16) & 1u;
    return (u + 0x7fffu + lsb) >> 16;
}
__device__ __forceinline__ ushort f2bf(float v) {
    return (ushort)f2bf_bits(v);
}

// swizzled band access: pixel line pIdx (128B), chunkB in {0,16,...,112}
__device__ __forceinline__ uint4 band_read(const ushort* smem, uint pIdx, uint chunkB) {
    uint off = pIdx * 128u + (chunkB ^ ((pIdx & 7u) << 4));
    return *(const uint4*)((const char*)smem + off);
}

// ---------------- prep ---------------- (unchanged, verified)
__global__ __launch_bounds__(256) void prep_kernel(
    const float* __restrict__ x, const float* __restrict__ w_off,
    const float* __restrict__ w_mask, const float* __restrict__ w_dcn,
    ushort* __restrict__ xTb, ushort* __restrict__ wOffB, ushort* __restrict__ wMainB)
{
    int blk = blockIdx.x;
    int t = threadIdx.x;
    if (blk < 1024) {
        __shared__ float L[64][128];
        int b = blk & 7, y = blk >> 3;
        const float* xb = x + (size_t)b * 1048576 + y * 128;
#pragma unroll
        for (int it = 0; it < 8; ++it) {
            int i = it * 256 + t;
            int c = i >> 5, x4 = i & 31;
            *(float4*)&L[c][x4 * 4] = *(const float4*)&xb[(size_t)c * HWt + x4 * 4];
        }
        __syncthreads();
        int px = t >> 1, half = (t & 1) * 32;
        union { ushort u[32]; uint4 q[4]; } pk;
#pragma unroll
        for (int i = 0; i < 32; ++i) pk.u[i] = f2bf(L[half + i][px]);
        uint4* dst = (uint4*)(xTb + ((size_t)(b * 128 + y) * 128 + px) * 64 + half);
        dst[0] = pk.q[0]; dst[1] = pk.q[1]; dst[2] = pk.q[2]; dst[3] = pk.q[3];
    } else {
        int i = (blk - 1024) * 256 + t;
        if (i < 9 * 32 * 64) {
            int c = i & 63, ch = (i >> 6) & 31, k = i >> 11;
            float v = 0.f;
            if (ch < 18)      v = w_off[(ch * 64 + c) * 9 + k];
            else if (ch < 27) v = w_mask[((ch - 18) * 64 + c) * 9 + k];
            wOffB[i] = f2bf(v);
        } else {
            int j = i - 18432;
            if (j < 9 * 64 * 64) {
                int c = j & 63, o = (j >> 6) & 63, k = j >> 12;
                wMainB[j] = f2bf(w_dcn[(o * 64 + c) * 9 + k]);
            }
        }
    }
}

// ---------------- phase-2 tap context ----------------
struct Tap { float w[4]; int pix[4]; uint gof[4]; uint inb; };

__device__ __forceinline__ void tap_ctx(int k, int ry, float cxf, int cq8,
                                        int row0, int col0,
                                        const float* __restrict__ odmRow, Tap& tp) {
    int ky = k / 3, kx = k - ky * 3;
    float dyv = odmRow[k];
    float dxv = odmRow[9 + k];
    float mkv = odmRow[18 + k];
    float py  = (float)(ry + ky - 1) + dyv;
    float pxf = cxf + (float)(kx - 1) + dxv;
    float y0f = floorf(py), x0f = floorf(pxf);
    float wy1 = py - y0f, wy0 = 1.f - wy1;
    float wx1 = pxf - x0f, wx0 = 1.f - wx1;
    bool vy0 = (y0f >= 0.f) && (y0f <= 127.f);
    bool vy1 = (y0f >= -1.f) && (y0f <= 126.f);
    bool vx0 = (x0f >= 0.f) && (x0f <= 127.f);
    bool vx1 = (x0f >= -1.f) && (x0f <= 126.f);
    tp.w[0] = (vy0 && vx0) ? wy0 * wx0 * mkv : 0.f;
    tp.w[1] = (vy0 && vx1) ? wy0 * wx1 * mkv : 0.f;
    tp.w[2] = (vy1 && vx0) ? wy1 * wx0 * mkv : 0.f;
    tp.w[3] = (vy1 && vx1) ? wy1 * wx1 * mkv : 0.f;
    int yi0 = (int)y0f, xi0 = (int)x0f;
    int y0c = min(max(yi0, 0), 127), y1c = min(max(yi0 + 1, 0), 127);
    int x0c = min(max(xi0, 0), 127), x1c = min(max(xi0 + 1, 0), 127);
    int by0 = y0c - row0, by1 = y1c - row0;
    int bx0 = x0c - col0, bx1 = x1c - col0;
    bool ry0 = (unsigned)by0 < (unsigned)BROWS, ry1 = (unsigned)by1 < (unsigned)BROWS;
    bool rx0 = (unsigned)bx0 < (unsigned)BCOLS, rx1 = (unsigned)bx1 < (unsigned)BCOLS;
    tp.inb = (uint)(ry0 && rx0) | ((uint)(ry0 && rx1) << 1)
           | ((uint)(ry1 && rx0) << 2) | ((uint)(ry1 && rx1) << 3);
    tp.pix[0] = by0 * BCOLS + bx0;
    tp.pix[1] = by0 * BCOLS + bx1;
    tp.pix[2] = by1 * BCOLS + bx0;
    tp.pix[3] = by1 * BCOLS + bx1;
    tp.gof[0] = (uint)(((y0c << 7) + x0c) * 64 + cq8);
    tp.gof[1] = (uint)(((y0c << 7) + x1c) * 64 + cq8);
    tp.gof[2] = (uint)(((y1c << 7) + x0c) * 64 + cq8);
    tp.gof[3] = (uint)(((y1c << 7) + x1c) * 64 + cq8);
}

// exact verified fmaf chain (bit-identical numerics)
__device__ __forceinline__ void tap_blend(const Tap& tp, const uint4* D, bf16x8* afr) {
    float w00 = tp.w[0], w01 = tp.w[1], w10 = tp.w[2], w11 = tp.w[3];
#pragma unroll
    for (int ks = 0; ks < 2; ++ks) {
        union { uint4 q; uint u[4]; } v00, v01, v10, v11, wr;
        v00.q = D[0 * 2 + ks];
        v01.q = D[1 * 2 + ks];
        v10.q = D[2 * 2 + ks];
        v11.q = D[3 * 2 + ks];
#pragma unroll
        for (int j = 0; j < 4; ++j) {
            float f00l = __uint_as_float(v00.u[j] << 16);
            float f00h = __uint_as_float(v00.u[j] & 0xffff0000u);
            float f01l = __uint_as_float(v01.u[j] << 16);
            float f01h = __uint_as_float(v01.u[j] & 0xffff0000u);
            float f10l = __uint_as_float(v10.u[j] << 16);
            float f10h = __uint_as_float(v10.u[j] & 0xffff0000u);
            float f11l = __uint_as_float(v11.u[j] << 16);
            float f11h = __uint_as_float(v11.u[j] & 0xffff0000u);
            float vl = w00 * f00l;
            vl = fmaf(w01, f01l, vl); vl = fmaf(w10, f10l, vl); vl = fmaf(w11, f11l, vl);
            float vh = w00 * f00h;
            vh = fmaf(w01, f01h, vh); vh = fmaf(w10, f10h, vh); vh = fmaf(w11, f11h, vh);
            wr.u[j] = (f2bf_bits(vh) << 16) | f2bf_bits(vl);
        }
        afr[ks] = __builtin_bit_cast(bf16x8, wr.q);
    }
}

// ---------------- fused: band-in-LDS offset conv + bilinear sample + MFMA ----------------
// block = one 16x8 pixel tile of one batch image; 512 thr, 8 waves x 16 px.
// Input band (20x12 px, 30.7KB, XOR-swizzled) staged ONCE; phase-1 A-reads and
// ~all phase-2 bilinear gathers come from the LDS pipe instead of vector-mem
// (TA) — the measured bottleneck. Rare out-of-band corners (|offset|>1) fall
// back to exec-masked global loads of the SAME values (bit-identical result).
// LDS 69,632 B -> 2 blocks/CU.
__global__ __launch_bounds__(512, 4) void dcn_fused_kernel(
    const ushort* __restrict__ xTb, const ushort* __restrict__ wOffB,
    const ushort* __restrict__ wMainB, const float* __restrict__ b_off,
    const float* __restrict__ b_mask, const float* __restrict__ b_dcn,
    float* __restrict__ out)
{
    __shared__ ushort smem[34816];               // 69,632 B
    float* odmF = (float*)((char*)smem + ODM_B); // [128][28] f32

    int t = threadIdx.x;
    int blk = blockIdx.x;
    int b = blk & 7;                 // XCD batch affinity
    int tile = blk >> 3;             // 0..127
    int rowBase = (tile >> 4) * 16;  // 8 row-tiles
    int colBase = (tile & 15) * 8;   // 16 col-tiles
    int wv = t >> 6, ln = t & 63;
    int m = ln & 15, cq = ln >> 4;
    int cq8 = cq * 8;
    int prow = 2 * wv + (m >> 3);    // tile-rel row of this lane's pixel
    int pcol = m & 7;                // tile-rel col
    int ry = rowBase + prow;         // image row
    int cx = colBase + pcol;         // image col

    const ushort* xbb = xTb + (size_t)b * 1048576;

    // ---------- stage band (1920 chunks) + wOff (2304 chunks) ----------
#pragma unroll
    for (int it = 0; it < 4; ++it) {
        int j = it * 512 + t;
        if (j < BPX * 8) {
            int pIdx = j >> 3, ch8 = j & 7;
            int br = pIdx / BCOLS, bc = pIdx - br * BCOLS;
            int iy = min(max(rowBase - 2 + br, 0), 127);
            int ix = min(max(colBase - 2 + bc, 0), 127);
            *(uint4*)((char*)smem + pIdx * 128 + ((ch8 * 16) ^ ((pIdx & 7) << 4))) =
                *(const uint4*)&xbb[(size_t)((iy << 7) + ix) * 64 + ch8 * 8];
        }
    }
#pragma unroll
    for (int it = 0; it < 5; ++it) {
        int j = it * 512 + t;
        if (j < 2304) {
            int row = j >> 3, gch = j & 7;
            int col = ((gch + row) & 7) * 8;
            *(uint4*)&smem[WBASE_U + row * 64 + col] = *(const uint4*)&wOffB[(size_t)row * 64 + gch * 8];
        }
    }
    __syncthreads();

    // ---------- phase 1: offset/mask conv (A from band LDS) ----------
    {
        f32x4 acc0 = {0.f, 0.f, 0.f, 0.f};
        f32x4 acc1 = {0.f, 0.f, 0.f, 0.f};
#pragma unroll
        for (int k = 0; k < 9; ++k) {
            int ky = k / 3, kx = k - ky * 3;
            int iyr = prow + ky - 1;
            int ixr = pcol + kx - 1;
            bool ok = ((unsigned)(rowBase + iyr) < 128u) && ((unsigned)(colBase + ixr) < 128u);
            uint pIdx = (uint)((iyr + 2) * BCOLS + (ixr + 2));   // always in-band
            uint4 a0 = band_read(smem, pIdx, cq8 * 2);
            uint4 a1 = band_read(smem, pIdx, cq8 * 2 + 64);
            if (!ok) { a0 = uint4{0u,0u,0u,0u}; a1 = uint4{0u,0u,0u,0u}; }
            int br0 = k * 32 + m;
            int br1 = br0 + 16;
#pragma unroll
            for (int ks = 0; ks < 2; ++ks) {
                bf16x8 afr = __builtin_bit_cast(bf16x8, ks ? a1 : a0);
                int gs = ks * 4 + cq;
                bf16x8 b0 = __builtin_bit_cast(bf16x8,
                    *(const uint4*)&smem[WBASE_U + br0 * 64 + ((gs + br0) & 7) * 8]);
                bf16x8 b1 = __builtin_bit_cast(bf16x8,
                    *(const uint4*)&smem[WBASE_U + br1 * 64 + ((gs + br1) & 7) * 8]);
                acc0 = __builtin_amdgcn_mfma_f32_16x16x32_bf16(afr, b0, acc0, 0, 0, 0);
                acc1 = __builtin_amdgcn_mfma_f32_16x16x32_bf16(afr, b1, acc1, 0, 0, 0);
            }
        }
        __syncthreads();   // wOff reads complete: odm + wS regions may be written

        // epilogue -> odm LDS.  slots: 0..8 = dy[k], 9..17 = dx[k], 18..26 = mask[k]
        int n = m;
        int pxl = wv * 16 + (cq << 2);
#pragma unroll
        for (int r = 0; r < 4; ++r) {
            int pp = pxl + r;
            odmF[pp * 28 + (n & 1) * 9 + (n >> 1)] = acc0[r] + b_off[n];
            int ch = 16 + n;
            float v1 = acc1[r];
            if (ch < 18) {
                odmF[pp * 28 + (ch & 1) * 9 + (ch >> 1)] = v1 + b_off[ch];
            } else if (ch < 27) {
                float val = v1 + b_mask[ch - 18];
                odmF[pp * 28 + 18 + (ch - 18)] = 1.f / (1.f + __expf(-val));
            }
        }

        // stage main-weight group 0 while epilogue drains
#pragma unroll
        for (int it = 0; it < 3; ++it) {
            int j = it * 512 + t;
            int row = j >> 3, gch = j & 7;
            *(uint4*)&smem[WBASE_U + row * 64 + ((gch + row) & 7) * 8] =
                *(const uint4*)&wMainB[(size_t)row * 64 + gch * 8];
        }
        __syncthreads();   // odm + group-0 weights visible
    }

    // ---------- phase 2: bilinear sample from band + main MFMA ----------
    f32x4 acc[4];
#pragma unroll
    for (int i = 0; i < 4; ++i) acc[i] = f32x4{0.f, 0.f, 0.f, 0.f};

    float cxf = (float)cx;
    const float* odmRow = odmF + (wv * 16 + m) * 28;
    const int row0 = rowBase - 2, col0 = colBase - 2;

#pragma unroll
    for (int k = 0; k < 9; ++k) {
        // group boundary: restage wS
        if (k == 3 || k == 6) {
            __syncthreads();
            const int gg = k / 3;
#pragma unroll
            for (int it = 0; it < 3; ++it) {
                int j = it * 512 + t;
                int row = j >> 3, gch = j & 7;
                *(uint4*)&smem[WBASE_U + row * 64 + ((gch + row) & 7) * 8] =
                    *(const uint4*)&wMainB[(size_t)(gg * 192 + row) * 64 + gch * 8];
            }
            __syncthreads();
        }

        Tap tp;
        tap_ctx(k, ry, cxf, cq8, row0, col0, odmRow, tp);

        uint4 D[8];
#pragma unroll
        for (int c = 0; c < 4; ++c) {
            bool ib = (tp.inb >> c) & 1u;
            uint pS = ib ? (uint)tp.pix[c] : 0u;
#pragma unroll
            for (int ks = 0; ks < 2; ++ks) {
                uint4 v = band_read(smem, pS, cq8 * 2 + ks * 64);
                if (!ib) v = *(const uint4*)(xbb + tp.gof[c] + ks * 32);  // rare fallback
                D[c * 2 + ks] = v;
            }
        }

        bf16x8 afr[2];
        tap_blend(tp, D, afr);

        const int tl = k - (k / 3) * 3;
#pragma unroll
        for (int ks = 0; ks < 2; ++ks) {
            int chk = ks * 4 + cq;
#pragma unroll
            for (int nt = 0; nt < 4; ++nt) {
                int brow = tl * 64 + nt * 16 + m;
                bf16x8 bb = __builtin_bit_cast(bf16x8,
                    *(const uint4*)&smem[WBASE_U + brow * 64 + ((chk + brow) & 7) * 8]);
                acc[nt] = __builtin_amdgcn_mfma_f32_16x16x32_bf16(afr[ks], bb, acc[nt], 0, 0, 0);
            }
        }
    }

    // epilogue: float4 stores (C row q = cq*4+r -> tile row 2wv+(cq>>1), col (cq&1)*4+r)
#pragma unroll
    for (int nt = 0; nt < 4; ++nt) {
        int o = nt * 16 + m;
        float bias = b_dcn[o];
        float4 v;
        v.x = acc[nt][0] + bias;
        v.y = acc[nt][1] + bias;
        v.z = acc[nt][2] + bias;
        v.w = acc[nt][3] + bias;
        float* orow = out + ((size_t)(b * 64 + o) << 14)
                    + (rowBase + 2 * wv + (cq >> 1)) * 128 + colBase + (cq & 1) * 4;
        *(float4*)orow = v;
    }
}

extern "C" void kernel_launch(void* const* d_in, const int* in_sizes, int n_in,
                              void* d_out, int out_size, void* d_ws, size_t ws_size,
                              hipStream_t stream) {
    const float* x      = (const float*)d_in[0];
    const float* w_off  = (const float*)d_in[1];
    const float* b_off  = (const float*)d_in[2];
    const float* w_mask = (const float*)d_in[3];
    const float* b_mask = (const float*)d_in[4];
    const float* w_dcn  = (const float*)d_in[5];
    const float* b_dcn  = (const float*)d_in[6];
    float* out = (float*)d_out;

    ushort* xTb    = (ushort*)d_ws;                  // 8.4M bf16
    ushort* wOffB  = xTb + (size_t)Bt * HWt * 64;    // 18432
    ushort* wMainB = wOffB + 18432;                  // 36864

    hipLaunchKernelGGL(prep_kernel, dim3(1024 + 216), dim3(256), 0, stream,
                       x, w_off, w_mask, w_dcn, xTb, wOffB, wMainB);
    hipLaunchKernelGGL(dcn_fused_kernel, dim3(1024), dim3(512), 0, stream,
                       xTb, wOffB, wMainB, b_off, b_mask, b_dcn, out);
}